// Round 7
// baseline (113.024 us; speedup 1.0000x reference)
//
#include <hip/hip_runtime.h>
#include <math.h>

#define NB   4      // n
#define C    128    // channels
#define S    31     // frames
#define HW   704    // h*w = 32*22
#define T    30     // s-1
#define NS   120    // n*(s-1)
#define K    16     // top_k

// ---------------------------------------------------------------------------
// Kernel 1: 1x1 conv (C->1), float4-vectorized, FULL-CHIP 341-block layout
// (~7.5us, at the HBM floor for the 44.7MB x read). Unchanged from round 6.
// ---------------------------------------------------------------------------
__global__ __launch_bounds__(256) void conv_kernel(
    const float* __restrict__ x,
    const float* __restrict__ w1, const float* __restrict__ b1p,
    const float* __restrict__ w2, const float* __restrict__ b2p,
    float* __restrict__ A, float* __restrict__ B) {
  const int tid  = threadIdx.x;
  const int lane = tid & 63;
  const int cg   = tid >> 6;                 // wave-uniform channel group
  const int g    = blockIdx.x * 64 + lane;   // float4 index, 0..21823
  const int fr   = g / 176;                  // (n, sf), 176 float4s per frame
  const int f4   = g % 176;
  const int sf   = fr % S;
  const int n    = fr / S;

  const float4* xp =
      (const float4*)(x + (((size_t)(n * C + cg * 32) * S + sf) * HW)) + f4;
  float4 a1 = make_float4(0.f, 0.f, 0.f, 0.f);
  float4 a2 = make_float4(0.f, 0.f, 0.f, 0.f);
#pragma unroll
  for (int c = 0; c < 32; ++c) {
    float4 xv = xp[(size_t)c * (S * HW / 4)];
    const float wa = w1[cg * 32 + c];        // wave-uniform -> s_load
    const float wb = w2[cg * 32 + c];
    a1.x = fmaf(xv.x, wa, a1.x); a1.y = fmaf(xv.y, wa, a1.y);
    a1.z = fmaf(xv.z, wa, a1.z); a1.w = fmaf(xv.w, wa, a1.w);
    a2.x = fmaf(xv.x, wb, a2.x); a2.y = fmaf(xv.y, wb, a2.y);
    a2.z = fmaf(xv.z, wb, a2.z); a2.w = fmaf(xv.w, wb, a2.w);
  }
  __shared__ float4 s1[4][64];
  __shared__ float4 s2[4][64];
  s1[cg][lane] = a1;
  s2[cg][lane] = a2;
  __syncthreads();
  if (tid < 64) {
    float4 r1 = s1[0][tid], r2 = s2[0][tid];
#pragma unroll
    for (int u = 1; u < 4; ++u) {
      float4 t1 = s1[u][tid], t2 = s2[u][tid];
      r1.x += t1.x; r1.y += t1.y; r1.z += t1.z; r1.w += t1.w;
      r2.x += t2.x; r2.y += t2.y; r2.z += t2.z; r2.w += t2.w;
    }
    const float bb1 = b1p[0], bb2 = b2p[0];
    r1.x += bb1; r1.y += bb1; r1.z += bb1; r1.w += bb1;
    r2.x += bb2; r2.y += bb2; r2.z += bb2; r2.w += bb2;
    if (sf < T)
      ((float4*)(A + (size_t)(n * T + sf) * HW))[f4] = r1;
    if (sf >= 1)
      ((float4*)(B + (size_t)(n * T + sf - 1) * HW))[f4] = r2;
  }
}

// ---------------------------------------------------------------------------
// Kernel 2: lane-serial softmax + in-block select, MERGED-SLAB blocks.
// Round-6 fit showed the redundant select costs ~6.7us at 1320 blocks
// (~3100-cycle serial wave-0 critical path paid per block). Select cost
// scales with block count; exp work doesn't. So: 120 pairs x 3 chunks
// (4/4/3 slabs) = 360 blocks x 1024 threads (16 waves, ~22 waves/CU).
// Per block: stage B row once, select once (redundancy 11x -> 3x), then
// wave w = slab_local (w>>2) x col-split q (w&3) runs the IDENTICAL
// per-slab lane-serial exp loop (176 exps/lane, same combine order ->
// bit-identical results). 4 epilogue waves run in parallel per block.
// ---------------------------------------------------------------------------
__global__ __launch_bounds__(1024) void softmax_select_kernel(
    const float* __restrict__ A, const float* __restrict__ B,
    float* __restrict__ out) {
  __shared__ float4 bs4[176];          // pair's full B row
  __shared__ float  partial[16][64];   // per-wave denominator partials
  __shared__ float  seltop[K], selbot[K];
  const int tid  = threadIdx.x;
  const int lane = tid & 63;
  const int w    = tid >> 6;                  // wave 0..15
  const int sl   = w >> 2;                    // slab_local 0..3
  const int q    = w & 3;                     // col-split 0..3
  const int i    = blockIdx.x / 3;            // frame pair
  const int c    = blockIdx.x % 3;            // slab chunk (4/4/3)
  const int sidx = c * 4 + sl;                // global slab 0..11
  const bool rowact = (sidx < 11);            // chunk 2 waves 12-15 idle
  const int n    = i / T;
  const int tp   = i % T;

  if (tid < 176) bs4[tid] = ((const float4*)(B + i * HW))[tid];
  const int   r = (rowact ? sidx : 10) * 64 + lane;  // clamped: always valid
  const float a = A[i * HW + r];
  __syncthreads();

  // wave 0: 16-round max/min extraction of the staged B row (once/block).
  // 704 = 11*64 values, 11/lane in registers, static indices only.
  if (tid < 64) {
    const float* bs = (const float*)&bs4[0];
    float vt[11], vb[11];
#pragma unroll
    for (int j = 0; j < 11; ++j) {
      const float v = bs[j * 64 + tid];       // stride-64: 2/bank = free
      vt[j] = v;
      vb[j] = v;
    }
#pragma unroll 1
    for (int rr = 0; rr < K; ++rr) {
      float lmT = vt[0], lmB = vb[0];
#pragma unroll
      for (int j = 1; j < 11; ++j) {
        lmT = fmaxf(lmT, vt[j]);
        lmB = fminf(lmB, vb[j]);
      }
      float gT = lmT, gB = lmB;
#pragma unroll
      for (int off = 1; off < 64; off <<= 1) {
        gT = fmaxf(gT, __shfl_xor(gT, off, 64));
        gB = fminf(gB, __shfl_xor(gB, off, 64));
      }
      const unsigned long long mT = __ballot(lmT == gT);
      const unsigned long long mB = __ballot(lmB == gB);
      if (tid == (int)(__ffsll(mT) - 1)) {
        bool done = false;
#pragma unroll
        for (int j = 0; j < 11; ++j) {
          const bool hit = (!done) && (vt[j] == gT);
          vt[j] = hit ? -INFINITY : vt[j];
          done  = done || hit;
        }
      }
      if (tid == (int)(__ffsll(mB) - 1)) {
        bool done = false;
#pragma unroll
        for (int j = 0; j < 11; ++j) {
          const bool hit = (!done) && (vb[j] == gB);
          vb[j] = hit ? INFINITY : vb[j];
          done  = done || hit;
        }
      }
      if (tid == 0) {
        seltop[rr] = gT;  // rr-th largest  -> descending
        selbot[rr] = gB;  // rr-th smallest -> ascending
      }
    }
  }
  __syncthreads();

  const float st0 = seltop[0];
  const float sb0 = selbot[0];
  const float L2E = 1.4426950408889634f;
  const float a2  = a * L2E;
  const float nm  = -((a >= 0.f) ? a * st0 : a * sb0) * L2E;

  // lane-serial denominator over this wave's 176-column span
  float p0 = 0.f, p1 = 0.f, p2 = 0.f, p3 = 0.f;
#pragma unroll 11
  for (int j = 0; j < 44; ++j) {
    const float4 bq = bs4[q * 44 + j];        // broadcast ds_read_b128
    p0 += __builtin_amdgcn_exp2f(fmaf(a2, bq.x, nm));
    p1 += __builtin_amdgcn_exp2f(fmaf(a2, bq.y, nm));
    p2 += __builtin_amdgcn_exp2f(fmaf(a2, bq.z, nm));
    p3 += __builtin_amdgcn_exp2f(fmaf(a2, bq.w, nm));
  }
  partial[w][lane] = (p0 + p1) + (p2 + p3);
  __syncthreads();

  if (q == 0 && rowact) {
    // combine the 4 col-split partials of this slab (waves w..w+3),
    // same association order as round 6 -> bit-identical
    const float part =
        (partial[w][lane] + partial[w + 1][lane]) +
        (partial[w + 2][lane] + partial[w + 3][lane]);
    const float rp = 1.f / part;
    float ov[16];
#pragma unroll
    for (int t = 0; t < K; ++t) {
      const float sel = (a >= 0.f) ? seltop[t] : selbot[t];
      ov[t] = __builtin_amdgcn_exp2f(fmaf(a2, sel, nm)) * rp;
    }
    // row r -> 16 contiguous floats at (n, r/44, tp, (r%44)*16)
    float* op = out + (((size_t)(n * K + r / 44)) * T + tp) * HW + (r % 44) * K;
#pragma unroll
    for (int t4 = 0; t4 < 4; ++t4)
      ((float4*)op)[t4] = ((const float4*)ov)[t4];
  }
}

extern "C" void kernel_launch(void* const* d_in, const int* in_sizes, int n_in,
                              void* d_out, int out_size, void* d_ws, size_t ws_size,
                              hipStream_t stream) {
  (void)in_sizes; (void)n_in; (void)out_size; (void)ws_size;
  const float* x  = (const float*)d_in[0];
  const float* w1 = (const float*)d_in[1];
  const float* b1 = (const float*)d_in[2];
  const float* w2 = (const float*)d_in[3];
  const float* b2 = (const float*)d_in[4];
  // d_in[5] is top_k (=16), hardcoded as K.
  float* out = (float*)d_out;

  float* A = (float*)d_ws;               // NS*HW
  float* B = A + NS * HW;                // NS*HW

  conv_kernel<<<341, 256, 0, stream>>>(x, w1, b1, w2, b2, A, B);
  softmax_select_kernel<<<NS * 3, 1024, 0, stream>>>(A, B, out);
}

// Round 8
// 107.302 us; speedup vs baseline: 1.0533x; 1.0533x over previous
//
#include <hip/hip_runtime.h>
#include <math.h>

#define NB   4      // n
#define C    128    // channels
#define S    31     // frames
#define HW   704    // h*w = 32*22
#define T    30     // s-1
#define NS   120    // n*(s-1)
#define K    16     // top_k

// ---------------------------------------------------------------------------
// Kernel 1: 1x1 conv (C->1) + PARTIAL per-chunk select. 124 frames x 3
// pixel-chunks = 372 blocks x 256 threads (full-chip fetch BW, unlike the
// 124-block whole-frame version that capped at 124/256 CUs -> 12.6us).
// Chunk c covers float4s [c*64, c*64+64) of the frame (chunk 2: 48 f4s).
// Structure per block = the proven conv341 block: 4 waves = 4 channel-
// groups of 32, lane = f4 within chunk, LDS combine. Then wave 0 extracts
// top/bot-16 OF THIS CHUNK's <=256 B-values (4 regs/lane, 16 rounds) and
// writes sorted partial lists. Only ~1 select-wave/CU, overlapped with
// other blocks' conv tails. Global top16 ⊆ union of chunk top16s.
// ---------------------------------------------------------------------------
__global__ __launch_bounds__(256) void conv_select_kernel(
    const float* __restrict__ x,
    const float* __restrict__ w1, const float* __restrict__ b1p,
    const float* __restrict__ w2, const float* __restrict__ b2p,
    float* __restrict__ A, float* __restrict__ B,
    float* __restrict__ ptop, float* __restrict__ pbot) {
  const int tid   = threadIdx.x;
  const int lane  = tid & 63;
  const int cg    = tid >> 6;                // wave-uniform channel group
  const int fr    = blockIdx.x / 3;          // frame 0..123
  const int chunk = blockIdx.x % 3;          // pixel chunk (64/64/48 f4s)
  const int sf    = fr % S;
  const int n     = fr / S;
  const int f4    = chunk * 64 + lane;
  const bool act  = f4 < 176;
  const int f4c   = act ? f4 : 175;          // idle lanes load a dup

  const float4* xp =
      (const float4*)(x + (((size_t)(n * C + cg * 32) * S + sf) * HW)) + f4c;
  float4 a1 = make_float4(0.f, 0.f, 0.f, 0.f);
  float4 a2 = make_float4(0.f, 0.f, 0.f, 0.f);
#pragma unroll
  for (int c = 0; c < 32; ++c) {
    float4 xv = xp[(size_t)c * (S * HW / 4)];
    const float wa = w1[cg * 32 + c];        // wave-uniform -> s_load
    const float wb = w2[cg * 32 + c];
    a1.x = fmaf(xv.x, wa, a1.x); a1.y = fmaf(xv.y, wa, a1.y);
    a1.z = fmaf(xv.z, wa, a1.z); a1.w = fmaf(xv.w, wa, a1.w);
    a2.x = fmaf(xv.x, wb, a2.x); a2.y = fmaf(xv.y, wb, a2.y);
    a2.z = fmaf(xv.z, wb, a2.z); a2.w = fmaf(xv.w, wb, a2.w);
  }
  __shared__ float4 s1[4][64];
  __shared__ float4 s2[4][64];
  s1[cg][lane] = a1;
  s2[cg][lane] = a2;
  __syncthreads();
  if (tid < 64) {
    float4 r1 = s1[0][tid], r2 = s2[0][tid];
#pragma unroll
    for (int u = 1; u < 4; ++u) {
      float4 t1 = s1[u][tid], t2 = s2[u][tid];
      r1.x += t1.x; r1.y += t1.y; r1.z += t1.z; r1.w += t1.w;
      r2.x += t2.x; r2.y += t2.y; r2.z += t2.z; r2.w += t2.w;
    }
    const float bb1 = b1p[0], bb2 = b2p[0];
    r1.x += bb1; r1.y += bb1; r1.z += bb1; r1.w += bb1;
    r2.x += bb2; r2.y += bb2; r2.z += bb2; r2.w += bb2;
    const bool act2 = (chunk * 64 + tid) < 176;
    if (act2) {
      if (sf < T)
        ((float4*)(A + (size_t)(n * T + sf) * HW))[chunk * 64 + tid] = r1;
      if (sf >= 1)
        ((float4*)(B + (size_t)(n * T + sf - 1) * HW))[chunk * 64 + tid] = r2;
    }
    // park biased B chunk values; floats [0,192) are always real,
    // [192,256) real only for chunks 0/1 (chunk 2 lanes 48-63 = garbage,
    // never read: reg 3 uses the pad path there)
    s2[0][tid] = r2;
  }
  __syncthreads();

  // wave 0: 16-round top/bot extraction of THIS CHUNK's values.
  if (tid < 64 && sf >= 1) {
    const int i = n * T + sf - 1;            // pair index
    const int nv = (chunk == 2) ? 3 : 4;     // real regs
    const float* bs = (const float*)&s2[0][0];
    float vt[4], vb[4];
#pragma unroll
    for (int j = 0; j < 3; ++j) {
      const float v = bs[j * 64 + tid];
      vt[j] = v; vb[j] = v;
    }
    if (nv == 4) { const float v = bs[192 + tid]; vt[3] = v; vb[3] = v; }
    else         { vt[3] = -INFINITY;         vb[3] = INFINITY; }
    float* pt = ptop + (i * 3 + chunk) * K;
    float* pb = pbot + (i * 3 + chunk) * K;
#pragma unroll 1
    for (int rr = 0; rr < K; ++rr) {
      float lmT = fmaxf(fmaxf(vt[0], vt[1]), fmaxf(vt[2], vt[3]));
      float lmB = fminf(fminf(vb[0], vb[1]), fminf(vb[2], vb[3]));
      float gT = lmT, gB = lmB;
#pragma unroll
      for (int off = 1; off < 64; off <<= 1) {
        gT = fmaxf(gT, __shfl_xor(gT, off, 64));
        gB = fminf(gB, __shfl_xor(gB, off, 64));
      }
      const unsigned long long mT = __ballot(lmT == gT);
      const unsigned long long mB = __ballot(lmB == gB);
      if (tid == (int)(__ffsll(mT) - 1)) {
        bool done = false;
#pragma unroll
        for (int j = 0; j < 4; ++j) {
          const bool hit = (!done) && (vt[j] == gT);
          vt[j] = hit ? -INFINITY : vt[j];
          done  = done || hit;
        }
      }
      if (tid == (int)(__ffsll(mB) - 1)) {
        bool done = false;
#pragma unroll
        for (int j = 0; j < 4; ++j) {
          const bool hit = (!done) && (vb[j] == gB);
          vb[j] = hit ? INFINITY : vb[j];
          done  = done || hit;
        }
      }
      if (tid == 0) { pt[rr] = gT; pb[rr] = gB; }   // sorted desc / asc
    }
  }
}

// ---------------------------------------------------------------------------
// Kernel 2: lane-serial softmax + BITONIC MERGE of the 3 partial lists.
// Grid = 120 pairs x 11 slabs = 1320 blocks x 256 threads (the r4 layout
// that measured ~3us). Wave 0 merges the three sorted desc top-16 lists
// (two 5-stage bitonic merges: desc‖reversed-asc input -> (lane&off)?min:
// max keeps desc), wave 1 merges the asc bottom lists with min/max swapped
// — ~100 cycles total, in parallel, replacing r6's 3100-cycle redundant
// extraction. Then the proven lane-serial denominator: lane r owns one
// output row, broadcast ds_read_b128 over the staged B row, LDS partial
// combine, no butterfly. m = exact row max of a*b so exponents <= 0.
// ---------------------------------------------------------------------------
__global__ __launch_bounds__(256) void softmax_merge_kernel(
    const float* __restrict__ A, const float* __restrict__ B,
    const float* __restrict__ ptop, const float* __restrict__ pbot,
    float* __restrict__ out) {
  __shared__ float4 bs4[176];         // pair's full B row
  __shared__ float  partial[4][64];   // per-wave denominator partials
  __shared__ float  seltop[K], selbot[K];
  const int tid  = threadIdx.x;
  const int lane = tid & 63;
  const int w    = tid >> 6;                  // wave 0..3 (q-split)
  const int i    = blockIdx.x / 11;           // frame pair
  const int slab = blockIdx.x % 11;
  const int n    = i / T;
  const int tp   = i % T;

  if (tid < 176) bs4[tid] = ((const float4*)(B + i * HW))[tid];
  const int   r = slab * 64 + lane;           // this lane's output row
  const float a = A[i * HW + r];

  if (w == 0) {            // merge top lists (desc)
    const float* pt = ptop + i * 3 * K;
    float e = -INFINITY;
    if (lane < 16)       e = pt[lane];        // L0 desc
    else if (lane < 32)  e = pt[47 - lane];   // L1 reversed -> asc
#pragma unroll
    for (int off = 16; off >= 1; off >>= 1) {
      const float xx = __shfl_xor(e, off, 64);
      e = (lane & off) ? fminf(e, xx) : fmaxf(e, xx);
    }
    if (lane >= 32)      e = -INFINITY;
    else if (lane >= 16) e = pt[63 - lane];   // L2 reversed -> asc
#pragma unroll
    for (int off = 16; off >= 1; off >>= 1) {
      const float xx = __shfl_xor(e, off, 64);
      e = (lane & off) ? fminf(e, xx) : fmaxf(e, xx);
    }
    if (lane < 16) seltop[lane] = e;
  } else if (w == 1) {     // merge bottom lists (asc)
    const float* pb = pbot + i * 3 * K;
    float e = INFINITY;
    if (lane < 16)       e = pb[lane];        // L0 asc
    else if (lane < 32)  e = pb[47 - lane];   // L1 reversed -> desc
#pragma unroll
    for (int off = 16; off >= 1; off >>= 1) {
      const float xx = __shfl_xor(e, off, 64);
      e = (lane & off) ? fmaxf(e, xx) : fminf(e, xx);
    }
    if (lane >= 32)      e = INFINITY;
    else if (lane >= 16) e = pb[63 - lane];   // L2 reversed -> desc
#pragma unroll
    for (int off = 16; off >= 1; off >>= 1) {
      const float xx = __shfl_xor(e, off, 64);
      e = (lane & off) ? fmaxf(e, xx) : fminf(e, xx);
    }
    if (lane < 16) selbot[lane] = e;
  }
  __syncthreads();

  const float st0 = seltop[0];
  const float sb0 = selbot[0];
  const float L2E = 1.4426950408889634f;
  const float a2  = a * L2E;
  const float nm  = -((a >= 0.f) ? a * st0 : a * sb0) * L2E;

  // lane-serial denominator over this wave's 176-column span
  float p0 = 0.f, p1 = 0.f, p2 = 0.f, p3 = 0.f;
#pragma unroll 11
  for (int j = 0; j < 44; ++j) {
    const float4 bq = bs4[w * 44 + j];        // broadcast ds_read_b128
    p0 += __builtin_amdgcn_exp2f(fmaf(a2, bq.x, nm));
    p1 += __builtin_amdgcn_exp2f(fmaf(a2, bq.y, nm));
    p2 += __builtin_amdgcn_exp2f(fmaf(a2, bq.z, nm));
    p3 += __builtin_amdgcn_exp2f(fmaf(a2, bq.w, nm));
  }
  partial[w][lane] = (p0 + p1) + (p2 + p3);
  __syncthreads();

  if (w == 0) {
    const float part =
        (partial[0][lane] + partial[1][lane]) +
        (partial[2][lane] + partial[3][lane]);
    const float rp = 1.f / part;
    float ov[16];
#pragma unroll
    for (int t = 0; t < K; ++t) {
      const float sel = (a >= 0.f) ? seltop[t] : selbot[t];
      ov[t] = __builtin_amdgcn_exp2f(fmaf(a2, sel, nm)) * rp;
    }
    // row r -> 16 contiguous floats at (n, r/44, tp, (r%44)*16)
    float* op = out + (((size_t)(n * K + r / 44)) * T + tp) * HW + (r % 44) * K;
#pragma unroll
    for (int t4 = 0; t4 < 4; ++t4)
      ((float4*)op)[t4] = ((const float4*)ov)[t4];
  }
}

extern "C" void kernel_launch(void* const* d_in, const int* in_sizes, int n_in,
                              void* d_out, int out_size, void* d_ws, size_t ws_size,
                              hipStream_t stream) {
  (void)in_sizes; (void)n_in; (void)out_size; (void)ws_size;
  const float* x  = (const float*)d_in[0];
  const float* w1 = (const float*)d_in[1];
  const float* b1 = (const float*)d_in[2];
  const float* w2 = (const float*)d_in[3];
  const float* b2 = (const float*)d_in[4];
  // d_in[5] is top_k (=16), hardcoded as K.
  float* out = (float*)d_out;

  float* A    = (float*)d_ws;            // NS*HW
  float* B    = A + NS * HW;             // NS*HW
  float* ptop = B + NS * HW;             // NS*3*K (per-chunk sorted desc)
  float* pbot = ptop + NS * 3 * K;       // NS*3*K (per-chunk sorted asc)

  conv_select_kernel<<<372, 256, 0, stream>>>(x, w1, b1, w2, b2,
                                              A, B, ptop, pbot);
  softmax_merge_kernel<<<NS * 11, 256, 0, stream>>>(A, B, ptop, pbot, out);
}